// Round 3
// baseline (1100.907 us; speedup 1.0000x reference)
//
#include <hip/hip_runtime.h>
#include <math.h>

typedef unsigned short u16;
typedef unsigned int u32;
typedef __bf16 bfx8 __attribute__((ext_vector_type(8)));
typedef float f32x4 __attribute__((ext_vector_type(4)));

#define NB 16
#define SS 512
#define NHD 16
#define DD 64
#define HD 1024
#define NROWS 8192
#define NEL 8388608  // 8192*1024

// scalar slots in ws (floats)
#define SL_AX_X 0
#define SL_AX_V 1
#define SL_MINSUM 2
#define SL_AX_CTX 3
#define SL_AX_QT 4   // 16 slots
#define SL_AX_KT 20  // 16 slots

struct PLA { float m[12]; float c[12]; float a[12]; };

__device__ __forceinline__ float b2f(u16 u) { return __uint_as_float(((u32)u) << 16); }
// exact for integer-valued floats |x|<=127 (low mantissa bits are zero)
__device__ __forceinline__ u16 f2b_exact(float f) { return (u16)(__float_as_uint(f) >> 16); }
__device__ __forceinline__ float mk_scale(float mx) { float s = mx / 127.0f; return (s == 0.0f) ? 1.0f : s; }
__device__ __forceinline__ float quant_val(float x, float s) {
  return fminf(fmaxf(rintf(x / s), -127.0f), 127.0f);
}
__device__ __forceinline__ float pla_eval(float x, const PLA& p) {
  float m = p.m[0], c = p.c[0];
#pragma unroll
  for (int i = 1; i < 12; i++) { if (x >= p.a[i]) { m = p.m[i]; c = p.c[i]; } }
  return __fadd_rn(__fmul_rn(m, x), c);
}
__device__ __forceinline__ float fixclip(float sh) {
  float t = rintf(__fmul_rn(sh, 67108864.0f));          // to_fixed_point frac_bits=26
  float fx = __fmul_rn(t, 1.4901161193847656e-08f);     // exact *2^-26
  return fmaxf(fminf(fx, 0.0f), -10.0f);
}

__global__ void k_init(float* scal) {
  int t = threadIdx.x;
  scal[t] = 0.0f;
  if (t == SL_MINSUM) scal[t] = __uint_as_float(0x7f800000u);  // +inf
}

// per-row absmax + quantize one weight matrix row (fp32) -> integer-valued bf16
__global__ void k_wprep(const float* __restrict__ W, float* __restrict__ sw, u16* __restrict__ wout) {
  int r = blockIdx.x;
  int tid = threadIdx.x;
  float4 v = ((const float4*)(W + (size_t)r * 1024))[tid];
  float m = fmaxf(fmaxf(fabsf(v.x), fabsf(v.y)), fmaxf(fabsf(v.z), fabsf(v.w)));
#pragma unroll
  for (int off = 32; off > 0; off >>= 1) m = fmaxf(m, __shfl_down(m, off));
  __shared__ float red[4];
  __shared__ float sbc;
  int lane = tid & 63, wv = tid >> 6;
  if (lane == 0) red[wv] = m;
  __syncthreads();
  if (tid == 0) sbc = mk_scale(fmaxf(fmaxf(red[0], red[1]), fmaxf(red[2], red[3])));
  __syncthreads();
  float s = sbc;
  if (tid == 0) sw[r] = s;
  u16 o0 = f2b_exact(quant_val(v.x, s));
  u16 o1 = f2b_exact(quant_val(v.y, s));
  u16 o2 = f2b_exact(quant_val(v.z, s));
  u16 o3 = f2b_exact(quant_val(v.w, s));
  u32* orow = (u32*)(wout + (size_t)r * 1024);
  orow[tid * 2] = (u32)o0 | ((u32)o1 << 16);
  orow[tid * 2 + 1] = (u32)o2 | ((u32)o3 << 16);
}

__global__ void k_absmax_f32(const float* __restrict__ x, int n, float* slot) {
  int tid = blockIdx.x * blockDim.x + threadIdx.x;
  int stride = gridDim.x * blockDim.x;
  const float4* x4 = (const float4*)x;
  int n4 = n >> 2;
  float m = 0.f;
  for (int j = tid; j < n4; j += stride) {
    float4 v = x4[j];
    m = fmaxf(m, fmaxf(fmaxf(fabsf(v.x), fabsf(v.y)), fmaxf(fabsf(v.z), fabsf(v.w))));
  }
#pragma unroll
  for (int off = 32; off > 0; off >>= 1) m = fmaxf(m, __shfl_down(m, off));
  __shared__ float red[4];
  if ((threadIdx.x & 63) == 0) red[threadIdx.x >> 6] = m;
  __syncthreads();
  if (threadIdx.x == 0) {
    m = fmaxf(fmaxf(red[0], red[1]), fmaxf(red[2], red[3]));
    atomicMax((u32*)slot, __float_as_uint(m));
  }
}

__global__ void k_quant_f32(const float* __restrict__ x, u16* __restrict__ o, const float* __restrict__ slot) {
  float s = mk_scale(*slot);
  int tid = blockIdx.x * blockDim.x + threadIdx.x;
  int stride = gridDim.x * blockDim.x;
  const float4* x4 = (const float4*)x;
  uint2* o2 = (uint2*)o;
  for (int j = tid; j < (NEL >> 2); j += stride) {
    float4 v = x4[j];
    u16 a = f2b_exact(quant_val(v.x, s));
    u16 b = f2b_exact(quant_val(v.y, s));
    u16 c = f2b_exact(quant_val(v.z, s));
    u16 d = f2b_exact(quant_val(v.w, s));
    uint2 w; w.x = (u32)a | ((u32)b << 16); w.y = (u32)c | ((u32)d << 16);
    o2[j] = w;
  }
}

// seq-tile absmax: layout [B,H,S,D]; block = (bh*16 + t), 2048 contiguous elements
__global__ void k_absmax_tiles(const float* __restrict__ x, float* slots) {
  int blk = blockIdx.x;
  int t = blk & 15;
  const float4* p = (const float4*)(x + (size_t)blk * 2048);
  float m = 0.f;
  for (int j = threadIdx.x; j < 512; j += 256) {
    float4 v = p[j];
    m = fmaxf(m, fmaxf(fmaxf(fabsf(v.x), fabsf(v.y)), fmaxf(fabsf(v.z), fabsf(v.w))));
  }
#pragma unroll
  for (int off = 32; off > 0; off >>= 1) m = fmaxf(m, __shfl_down(m, off));
  __shared__ float red[4];
  if ((threadIdx.x & 63) == 0) red[threadIdx.x >> 6] = m;
  __syncthreads();
  if (threadIdx.x == 0) {
    m = fmaxf(fmaxf(red[0], red[1]), fmaxf(red[2], red[3]));
    atomicMax((u32*)&slots[t], __float_as_uint(m));
  }
}

__global__ void k_quant_tiles(const float* __restrict__ x, u16* __restrict__ o, const float* __restrict__ slots) {
  int tid = blockIdx.x * blockDim.x + threadIdx.x;
  int stride = gridDim.x * blockDim.x;
  const float4* x4 = (const float4*)x;
  uint2* o2 = (uint2*)o;
  for (int j = tid; j < (NEL >> 2); j += stride) {
    int e = j << 2;
    float s = mk_scale(slots[(e >> 11) & 15]);
    float4 v = x4[j];
    u16 a = f2b_exact(quant_val(v.x, s));
    u16 b = f2b_exact(quant_val(v.y, s));
    u16 c = f2b_exact(quant_val(v.z, s));
    u16 d = f2b_exact(quant_val(v.w, s));
    uint2 w; w.x = (u32)a | ((u32)b << 16); w.y = (u32)c | ((u32)d << 16);
    o2[j] = w;
  }
}

// quantize v (global scale) and transpose [B,H,S,D] -> [B,H,D,S]
__global__ void k_quant_vT(const float* __restrict__ x, u16* __restrict__ o, const float* __restrict__ slot) {
  __shared__ u16 lds[64][136];
  float s = mk_scale(*slot);
  int bh = blockIdx.x >> 2;
  int sc0 = (blockIdx.x & 3) << 7;  // 128-row s chunk
  const float4* src = (const float4*)(x + ((size_t)bh * SS + sc0) * DD);
  for (int j = threadIdx.x; j < 2048; j += 256) {
    float4 v = src[j];
    int e = j << 2;
    int srow = e >> 6, d = e & 63;
    lds[d][srow] = f2b_exact(quant_val(v.x, s));
    lds[d + 1][srow] = f2b_exact(quant_val(v.y, s));
    lds[d + 2][srow] = f2b_exact(quant_val(v.z, s));
    lds[d + 3][srow] = f2b_exact(quant_val(v.w, s));
  }
  __syncthreads();
  int d = threadIdx.x >> 2, s0 = (threadIdx.x & 3) << 5;
  u16* dst = o + ((size_t)bh * DD + d) * SS + sc0 + s0;
#pragma unroll
  for (int i = 0; i < 32; i += 8)
    *(uint4*)(dst + i) = *(const uint4*)&lds[d][s0 + i];
}

// C[M,N] = A[M,K] * B[N,K]^T  (both integer-valued bf16; exact in fp32 MFMA accum)
// epilogue: val = acc * (sa*sb[n]) + bias[n]; mode1 -> fp32 [B,NH,S,D]; mode0 -> fp32 [M,N]
__global__ __launch_bounds__(256) void k_gemm(const u16* __restrict__ A, const u16* __restrict__ Bw,
    const float* __restrict__ axslot, const float* __restrict__ sb, const float* __restrict__ bias,
    float* outf, float* outc, int mode) {
  __shared__ u16 As[128][72];
  __shared__ u16 Bs[128][72];
  int tid = threadIdx.x;
  int bm = blockIdx.x << 7, bn = blockIdx.y << 7;
  int wv = tid >> 6, lane = tid & 63, quad = lane >> 4, l16 = lane & 15;
  int wr = (wv >> 1) << 6, wc = (wv & 1) << 6;
  int sr = tid >> 1, sseg = (tid & 1) << 5;
  const u16* Ag = A + (size_t)(bm + sr) * 1024 + sseg;
  const u16* Bg = Bw + (size_t)(bn + sr) * 1024 + sseg;
  f32x4 zero = {0.f, 0.f, 0.f, 0.f};
  f32x4 acc[4][4];
#pragma unroll
  for (int i = 0; i < 4; i++)
#pragma unroll
    for (int j = 0; j < 4; j++) acc[i][j] = zero;
  for (int k0 = 0; k0 < 1024; k0 += 64) {
    // each thread covers K-columns [sseg, sseg+32) of its row: full 64-wide tile with 2 threads/row
    uint4 av0 = *(const uint4*)(Ag + k0);
    uint4 av1 = *(const uint4*)(Ag + k0 + 8);
    uint4 av2 = *(const uint4*)(Ag + k0 + 16);
    uint4 av3 = *(const uint4*)(Ag + k0 + 24);
    uint4 bv0 = *(const uint4*)(Bg + k0);
    uint4 bv1 = *(const uint4*)(Bg + k0 + 8);
    uint4 bv2 = *(const uint4*)(Bg + k0 + 16);
    uint4 bv3 = *(const uint4*)(Bg + k0 + 24);
    __syncthreads();
    *(uint4*)&As[sr][sseg] = av0;      *(uint4*)&As[sr][sseg + 8] = av1;
    *(uint4*)&As[sr][sseg + 16] = av2; *(uint4*)&As[sr][sseg + 24] = av3;
    *(uint4*)&Bs[sr][sseg] = bv0;      *(uint4*)&Bs[sr][sseg + 8] = bv1;
    *(uint4*)&Bs[sr][sseg + 16] = bv2; *(uint4*)&Bs[sr][sseg + 24] = bv3;
    __syncthreads();
#pragma unroll
    for (int ks = 0; ks < 2; ks++) {
      bfx8 af[4], bfr[4];
#pragma unroll
      for (int i = 0; i < 4; i++) {
        af[i] = *(const bfx8*)&As[wr + i * 16 + l16][ks * 32 + quad * 8];
        bfr[i] = *(const bfx8*)&Bs[wc + i * 16 + l16][ks * 32 + quad * 8];
      }
#pragma unroll
      for (int i = 0; i < 4; i++)
#pragma unroll
        for (int j = 0; j < 4; j++)
          acc[i][j] = __builtin_amdgcn_mfma_f32_16x16x32_bf16(af[i], bfr[j], acc[i][j], 0, 0, 0);
    }
  }
  float sa = mk_scale(*axslot);
#pragma unroll
  for (int j = 0; j < 4; j++) {
    int col = bn + wc + j * 16 + l16;
    float sc = __fmul_rn(sa, sb[col]);
    float bi = bias[col];
#pragma unroll
    for (int i = 0; i < 4; i++) {
      int row0 = bm + wr + i * 16 + quad * 4;
#pragma unroll
      for (int r = 0; r < 4; r++) {
        float v = __fadd_rn(__fmul_rn(acc[i][j][r], sc), bi);
        int row = row0 + r;
        if (mode) {
          int b = row >> 9, s2 = row & 511, h = col >> 6, d = col & 63;
          outf[((((size_t)b * NHD) + h) * SS + s2) * DD + d] = v;
        } else {
          outc[(size_t)row * HD + col] = v;
        }
      }
    }
  }
}

// pass 1: rowmax of scaled scores, PLA row sums, atomic-min(rowsum)
__global__ __launch_bounds__(256) void k_attn1(const u16* __restrict__ qq, const u16* __restrict__ kq,
    float* scal, float* __restrict__ rowmax, float* __restrict__ rowsum, PLA pla) {
  int blk = blockIdx.x;
  int bh = blk >> 3;
  int q0 = (blk & 7) << 6;
  int tid = threadIdx.x;
  int wv = tid >> 6, lane = tid & 63, quad = lane >> 4, l16 = lane & 15;
  int rowb = q0 + wv * 16;
  const u16* qbase = qq + ((size_t)bh * SS + rowb) * DD;
  const u16* kbase = kq + (size_t)bh * SS * DD;
  bfx8 a0 = *(const bfx8*)(qbase + l16 * DD + quad * 8);
  bfx8 a1 = *(const bfx8*)(qbase + l16 * DD + 32 + quad * 8);
  float sqv = mk_scale(scal[SL_AX_QT + (rowb >> 5)]);
  float rm[4] = {-INFINITY, -INFINITY, -INFINITY, -INFINITY};
  for (int cb = 0; cb < 32; cb++) {
    const u16* kp = kbase + (size_t)(cb * 16 + l16) * DD + quad * 8;
    bfx8 b0 = *(const bfx8*)kp;
    bfx8 b1 = *(const bfx8*)(kp + 32);
    f32x4 acc = {0.f, 0.f, 0.f, 0.f};
    acc = __builtin_amdgcn_mfma_f32_16x16x32_bf16(a0, b0, acc, 0, 0, 0);
    acc = __builtin_amdgcn_mfma_f32_16x16x32_bf16(a1, b1, acc, 0, 0, 0);
    float sk = mk_scale(scal[SL_AX_KT + (cb >> 1)]);
    float sc = __fmul_rn(__fmul_rn(0.125f, sqv), sk);
#pragma unroll
    for (int r = 0; r < 4; r++) rm[r] = fmaxf(rm[r], __fmul_rn(acc[r], sc));
  }
#pragma unroll
  for (int m = 1; m < 16; m <<= 1)
#pragma unroll
    for (int r = 0; r < 4; r++) rm[r] = fmaxf(rm[r], __shfl_xor(rm[r], m));
  float sums[4] = {0.f, 0.f, 0.f, 0.f};
  for (int cb = 0; cb < 32; cb++) {
    const u16* kp = kbase + (size_t)(cb * 16 + l16) * DD + quad * 8;
    bfx8 b0 = *(const bfx8*)kp;
    bfx8 b1 = *(const bfx8*)(kp + 32);
    f32x4 acc = {0.f, 0.f, 0.f, 0.f};
    acc = __builtin_amdgcn_mfma_f32_16x16x32_bf16(a0, b0, acc, 0, 0, 0);
    acc = __builtin_amdgcn_mfma_f32_16x16x32_bf16(a1, b1, acc, 0, 0, 0);
    float sk = mk_scale(scal[SL_AX_KT + (cb >> 1)]);
    float sc = __fmul_rn(__fmul_rn(0.125f, sqv), sk);
#pragma unroll
    for (int r = 0; r < 4; r++) {
      float sh = __fsub_rn(__fmul_rn(acc[r], sc), rm[r]);
      sums[r] += pla_eval(fixclip(sh), pla);
    }
  }
#pragma unroll
  for (int m = 1; m < 16; m <<= 1)
#pragma unroll
    for (int r = 0; r < 4; r++) sums[r] += __shfl_xor(sums[r], m);
  if (l16 == 0) {
#pragma unroll
    for (int r = 0; r < 4; r++) {
      int row = bh * SS + rowb + quad * 4 + r;
      rowmax[row] = rm[r];
      rowsum[row] = sums[r];
      atomicMin((u32*)&scal[SL_MINSUM], __float_as_uint(sums[r]));
    }
  }
}

// pass 2: recompute scores, quantize probs (global scale from minsum), PV, write ctx fp32 [B,S,H*D]
__global__ __launch_bounds__(256) void k_attn2(const u16* __restrict__ qq, const u16* __restrict__ kq,
    const u16* __restrict__ vqt, const float* scal, const float* __restrict__ rowmax,
    const float* __restrict__ rowsum, float* __restrict__ ctx, PLA pla) {
  __shared__ u16 P[32][520];
  int blk = blockIdx.x;
  int bh = blk >> 4;
  int q0 = (blk & 15) << 5;
  int tid = threadIdx.x;
  int wv = tid >> 6, lane = tid & 63, quad = lane >> 4, l16 = lane & 15;
  int rb = (wv >> 1) * 16;
  int cb0 = (wv & 1) * 16;
  const u16* qbase = qq + ((size_t)bh * SS + q0 + rb) * DD;
  const u16* kbase = kq + (size_t)bh * SS * DD;
  bfx8 a0 = *(const bfx8*)(qbase + l16 * DD + quad * 8);
  bfx8 a1 = *(const bfx8*)(qbase + l16 * DD + 32 + quad * 8);
  float sqv = mk_scale(scal[SL_AX_QT + (q0 >> 5)]);
  float rmx[4], rsm[4];
#pragma unroll
  for (int r = 0; r < 4; r++) {
    int row = bh * SS + q0 + rb + quad * 4 + r;
    rmx[r] = rowmax[row];
    rsm[r] = rowsum[row] + 1e-9f;
  }
  float minsum = scal[SL_MINSUM];
  float mxsm = pla.c[11] / (minsum + 1e-9f);   // == global max(sm): PLA monotone, every row attains x=0
  float scp = mk_scale(mxsm);
  for (int cb = cb0; cb < cb0 + 16; cb++) {
    const u16* kp = kbase + (size_t)(cb * 16 + l16) * DD + quad * 8;
    bfx8 b0 = *(const bfx8*)kp;
    bfx8 b1 = *(const bfx8*)(kp + 32);
    f32x4 acc = {0.f, 0.f, 0.f, 0.f};
    acc = __builtin_amdgcn_mfma_f32_16x16x32_bf16(a0, b0, acc, 0, 0, 0);
    acc = __builtin_amdgcn_mfma_f32_16x16x32_bf16(a1, b1, acc, 0, 0, 0);
    float sk = mk_scale(scal[SL_AX_KT + (cb >> 1)]);
    float sc = __fmul_rn(__fmul_rn(0.125f, sqv), sk);
#pragma unroll
    for (int r = 0; r < 4; r++) {
      float sh = __fsub_rn(__fmul_rn(acc[r], sc), rmx[r]);
      float e = pla_eval(fixclip(sh), pla);
      float smv = e / rsm[r];
      float np = fminf(fmaxf(rintf(smv / scp), -127.0f), 127.0f);
      P[rb + quad * 4 + r][cb * 16 + l16] = f2b_exact(np);
    }
  }
  __syncthreads();
  f32x4 acc2[2];
  f32x4 zero = {0.f, 0.f, 0.f, 0.f};
  acc2[0] = zero; acc2[1] = zero;
  const u16* vb = vqt + (size_t)bh * DD * SS;
  int dbase = (wv & 1) * 32;
  int rb2 = (wv >> 1) * 16;
  for (int ks = 0; ks < 16; ks++) {
    bfx8 pa = *(const bfx8*)&P[rb2 + l16][ks * 32 + quad * 8];
#pragma unroll
    for (int j = 0; j < 2; j++) {
      int d = dbase + j * 16 + l16;
      bfx8 vf = *(const bfx8*)(vb + (size_t)d * SS + ks * 32 + quad * 8);
      acc2[j] = __builtin_amdgcn_mfma_f32_16x16x32_bf16(pa, vf, acc2[j], 0, 0, 0);
    }
  }
  float sv = mk_scale(scal[SL_AX_V]);
  float fsc = __fmul_rn(scp, sv);
  int b = bh >> 4, h = bh & 15;
#pragma unroll
  for (int j = 0; j < 2; j++) {
    int d = dbase + j * 16 + l16;
#pragma unroll
    for (int r = 0; r < 4; r++) {
      int srow = q0 + rb2 + quad * 4 + r;
      ctx[((size_t)(b * SS + srow)) * HD + h * DD + d] = __fmul_rn(acc2[j][r], fsc);
    }
  }
}

// host: rebuild _build_pla exactly (float64 linspace mirror + degree-1 OLS, cast to f32)
static void build_pla(PLA* p) {
  double xs[1001], ys[1001];
  for (int i = 0; i < 1001; i++) { double t = (double)i * 0.01; xs[i] = t - 10.0; }
  xs[1000] = 0.0;
  for (int i = 0; i < 1001; i++) ys[i] = exp(xs[i]);
  double es = 10.0 / 12.0;
  double edges[13];
  for (int i = 0; i < 13; i++) { double t = (double)i * es; edges[i] = t - 10.0; }
  edges[12] = 0.0;
  for (int k = 0; k < 12; k++) {
    double sx = 0, sy = 0, sxx = 0, sxy = 0; int n = 0;
    for (int j = 0; j < 1001; j++) {
      if (xs[j] >= edges[k] && xs[j] <= edges[k + 1]) {
        n++; sx += xs[j]; sy += ys[j]; sxx += xs[j] * xs[j]; sxy += xs[j] * ys[j];
      }
    }
    double mx = sx / n, my = sy / n;
    double mm = (sxy - sx * my) / (sxx - sx * mx);
    double cc = my - mm * mx;
    p->m[k] = (float)mm; p->c[k] = (float)cc; p->a[k] = (float)edges[k];
  }
}

extern "C" void kernel_launch(void* const* d_in, const int* in_sizes, int n_in,
                              void* d_out, int out_size, void* d_ws, size_t ws_size,
                              hipStream_t stream) {
  const float* hs = (const float*)d_in[0];
  const float* Wq = (const float*)d_in[1]; const float* bq = (const float*)d_in[2];
  const float* Wk = (const float*)d_in[3]; const float* bk = (const float*)d_in[4];
  const float* Wv = (const float*)d_in[5]; const float* bv = (const float*)d_in[6];
  const float* Wo = (const float*)d_in[7]; const float* bo = (const float*)d_in[8];
  float* out = (float*)d_out;
  char* ws = (char*)d_ws;
  float* scal = (float*)ws;                         // 64 scalar slots
  float* sw = (float*)(ws + 4096);                  // 4*1024 per-row weight scales
  float* rowmax = (float*)(ws + (64 << 10));        // 131072 f32
  float* rowsum = (float*)(ws + (576 << 10));       // 131072 f32
  u16* wb = (u16*)(ws + (2ll << 20));               // 4 x [1024,1024] bf16-int
  u16* xq = (u16*)(ws + (10ll << 20));              // [8192,1024] bf16-int (later reused as ctxq)
  u16* qq = (u16*)(ws + (26ll << 20));              // [B,H,S,D]
  u16* kq = (u16*)(ws + (42ll << 20));              // [B,H,S,D]
  u16* vqt = (u16*)(ws + (58ll << 20));             // [B,H,D,S]
  float* tmp = (float*)(ws + (74ll << 20));         // [8192,1024] fp32 temp (q/k/v then ctx)
  u16* ctxq = xq;

  PLA pla;
  build_pla(&pla);

  k_init<<<1, 64, 0, stream>>>(scal);
  k_wprep<<<1024, 256, 0, stream>>>(Wq, sw + 0, wb + 0);
  k_wprep<<<1024, 256, 0, stream>>>(Wk, sw + 1024, wb + 1048576);
  k_wprep<<<1024, 256, 0, stream>>>(Wv, sw + 2048, wb + 2097152);
  k_wprep<<<1024, 256, 0, stream>>>(Wo, sw + 3072, wb + 3145728);
  k_absmax_f32<<<512, 256, 0, stream>>>(hs, NEL, scal + SL_AX_X);
  k_quant_f32<<<1024, 256, 0, stream>>>(hs, xq, scal + SL_AX_X);

  const float* biases[3] = {bq, bk, bv};
  for (int z = 0; z < 3; z++) {
    k_gemm<<<dim3(64, 8), 256, 0, stream>>>(xq, wb + (size_t)z * 1048576, scal + SL_AX_X,
                                            sw + z * 1024, biases[z], tmp, (float*)0, 1);
    if (z == 0) {
      k_absmax_tiles<<<4096, 256, 0, stream>>>(tmp, scal + SL_AX_QT);
      k_quant_tiles<<<1024, 256, 0, stream>>>(tmp, qq, scal + SL_AX_QT);
    } else if (z == 1) {
      k_absmax_tiles<<<4096, 256, 0, stream>>>(tmp, scal + SL_AX_KT);
      k_quant_tiles<<<1024, 256, 0, stream>>>(tmp, kq, scal + SL_AX_KT);
    } else {
      k_absmax_f32<<<512, 256, 0, stream>>>(tmp, NEL, scal + SL_AX_V);
      k_quant_vT<<<1024, 256, 0, stream>>>(tmp, vqt, scal + SL_AX_V);
    }
  }

  k_attn1<<<2048, 256, 0, stream>>>(qq, kq, scal, rowmax, rowsum, pla);
  k_attn2<<<4096, 256, 0, stream>>>(qq, kq, vqt, scal, rowmax, rowsum, tmp, pla);

  k_absmax_f32<<<512, 256, 0, stream>>>(tmp, NEL, scal + SL_AX_CTX);
  k_quant_f32<<<1024, 256, 0, stream>>>(tmp, ctxq, scal + SL_AX_CTX);
  k_gemm<<<dim3(64, 8), 256, 0, stream>>>(ctxq, wb + 3145728, scal + SL_AX_CTX,
                                          sw + 3072, bo, (float*)0, out, 0);
}

// Round 4
// 607.101 us; speedup vs baseline: 1.8134x; 1.8134x over previous
//
#include <hip/hip_runtime.h>
#include <math.h>

typedef unsigned short u16;
typedef unsigned int u32;
typedef __bf16 bfx8 __attribute__((ext_vector_type(8)));
typedef float f32x4 __attribute__((ext_vector_type(4)));

#define NB 16
#define SS 512
#define NHD 16
#define DD 64
#define HD 1024
#define NROWS 8192
#define NEL 8388608  // 8192*1024

// scalar slots in ws (floats)
#define SL_AX_X 0
#define SL_AX_V 1
#define SL_MINSUM 2
#define SL_AX_CTX 3
#define SL_AX_QT 4   // 16 slots
#define SL_AX_KT 20  // 16 slots

struct PLA { float m[12]; float c[12]; float a[12]; };

__device__ __forceinline__ float b2f(u16 u) { return __uint_as_float(((u32)u) << 16); }
// exact for integer-valued floats |x|<=127 (low mantissa bits are zero)
__device__ __forceinline__ u16 f2b_exact(float f) { return (u16)(__float_as_uint(f) >> 16); }
__device__ __forceinline__ float mk_scale(float mx) { float s = mx / 127.0f; return (s == 0.0f) ? 1.0f : s; }
__device__ __forceinline__ float quant_val(float x, float s) {
  return fminf(fmaxf(rintf(x / s), -127.0f), 127.0f);
}
__device__ __forceinline__ float fixclip(float sh) {
  float t = rintf(__fmul_rn(sh, 67108864.0f));          // to_fixed_point frac_bits=26
  float fx = __fmul_rn(t, 1.4901161193847656e-08f);     // exact *2^-26
  return fmaxf(fminf(fx, 0.0f), -10.0f);
}
// fast PLA via uniform-interval guess + 1 correction; tbl[i] = {a[i], a[i+1](or 1e30), m[i], c[i]}
// exactly replicates searchsorted(a, xc, 'right')-1 then m*x+c (separate f32 mul+add)
__device__ __forceinline__ float pla_fast(float xc, const float (*tbl)[4]) {
  int idx = (int)floorf(__fmul_rn(__fadd_rn(xc, 10.0f), 1.2f));
  idx = idx < 0 ? 0 : (idx > 11 ? 11 : idx);
  float4 tv = *(const float4*)tbl[idx];
  int up = (xc >= tv.y) ? 1 : 0;       // never true at idx==11 (sentinel 1e30)
  int dn = (xc < tv.x) ? 1 : 0;        // never true at idx==0 (a[0]=-10 <= xc)
  idx += up - dn;
  float4 tv2 = *(const float4*)tbl[idx];
  return __fadd_rn(__fmul_rn(tv2.z, xc), tv2.w);
}

__global__ void k_init(float* scal) {
  int t = threadIdx.x;
  scal[t] = 0.0f;
  if (t == SL_MINSUM) scal[t] = __uint_as_float(0x7f800000u);  // +inf
}

// per-row absmax + quantize one weight matrix row (fp32) -> integer-valued bf16
__global__ void k_wprep(const float* __restrict__ W, float* __restrict__ sw, u16* __restrict__ wout) {
  int r = blockIdx.x;
  int tid = threadIdx.x;
  float4 v = ((const float4*)(W + (size_t)r * 1024))[tid];
  float m = fmaxf(fmaxf(fabsf(v.x), fabsf(v.y)), fmaxf(fabsf(v.z), fabsf(v.w)));
#pragma unroll
  for (int off = 32; off > 0; off >>= 1) m = fmaxf(m, __shfl_down(m, off));
  __shared__ float red[4];
  __shared__ float sbc;
  int lane = tid & 63, wv = tid >> 6;
  if (lane == 0) red[wv] = m;
  __syncthreads();
  if (tid == 0) sbc = mk_scale(fmaxf(fmaxf(red[0], red[1]), fmaxf(red[2], red[3])));
  __syncthreads();
  float s = sbc;
  if (tid == 0) sw[r] = s;
  u16 o0 = f2b_exact(quant_val(v.x, s));
  u16 o1 = f2b_exact(quant_val(v.y, s));
  u16 o2 = f2b_exact(quant_val(v.z, s));
  u16 o3 = f2b_exact(quant_val(v.w, s));
  u32* orow = (u32*)(wout + (size_t)r * 1024);
  orow[tid * 2] = (u32)o0 | ((u32)o1 << 16);
  orow[tid * 2 + 1] = (u32)o2 | ((u32)o3 << 16);
}

__global__ void k_absmax_f32(const float* __restrict__ x, int n, float* slot) {
  int tid = blockIdx.x * blockDim.x + threadIdx.x;
  int stride = gridDim.x * blockDim.x;
  const float4* x4 = (const float4*)x;
  int n4 = n >> 2;
  float m = 0.f;
  for (int j = tid; j < n4; j += stride) {
    float4 v = x4[j];
    m = fmaxf(m, fmaxf(fmaxf(fabsf(v.x), fabsf(v.y)), fmaxf(fabsf(v.z), fabsf(v.w))));
  }
#pragma unroll
  for (int off = 32; off > 0; off >>= 1) m = fmaxf(m, __shfl_down(m, off));
  __shared__ float red[4];
  if ((threadIdx.x & 63) == 0) red[threadIdx.x >> 6] = m;
  __syncthreads();
  if (threadIdx.x == 0) {
    m = fmaxf(fmaxf(red[0], red[1]), fmaxf(red[2], red[3]));
    atomicMax((u32*)slot, __float_as_uint(m));
  }
}

__global__ void k_quant_f32(const float* __restrict__ x, u16* __restrict__ o, const float* __restrict__ slot) {
  float s = mk_scale(*slot);
  int tid = blockIdx.x * blockDim.x + threadIdx.x;
  int stride = gridDim.x * blockDim.x;
  const float4* x4 = (const float4*)x;
  uint2* o2 = (uint2*)o;
  for (int j = tid; j < (NEL >> 2); j += stride) {
    float4 v = x4[j];
    u16 a = f2b_exact(quant_val(v.x, s));
    u16 b = f2b_exact(quant_val(v.y, s));
    u16 c = f2b_exact(quant_val(v.z, s));
    u16 d = f2b_exact(quant_val(v.w, s));
    uint2 w; w.x = (u32)a | ((u32)b << 16); w.y = (u32)c | ((u32)d << 16);
    o2[j] = w;
  }
}

// seq-tile absmax: layout [B,H,S,D]; block = (bh*16 + t), 2048 contiguous elements
__global__ void k_absmax_tiles(const float* __restrict__ x, float* slots) {
  int blk = blockIdx.x;
  int t = blk & 15;
  const float4* p = (const float4*)(x + (size_t)blk * 2048);
  float m = 0.f;
  for (int j = threadIdx.x; j < 512; j += 256) {
    float4 v = p[j];
    m = fmaxf(m, fmaxf(fmaxf(fabsf(v.x), fabsf(v.y)), fmaxf(fabsf(v.z), fabsf(v.w))));
  }
#pragma unroll
  for (int off = 32; off > 0; off >>= 1) m = fmaxf(m, __shfl_down(m, off));
  __shared__ float red[4];
  if ((threadIdx.x & 63) == 0) red[threadIdx.x >> 6] = m;
  __syncthreads();
  if (threadIdx.x == 0) {
    m = fmaxf(fmaxf(red[0], red[1]), fmaxf(red[2], red[3]));
    atomicMax((u32*)&slots[t], __float_as_uint(m));
  }
}

__global__ void k_quant_tiles(const float* __restrict__ x, u16* __restrict__ o, const float* __restrict__ slots) {
  int tid = blockIdx.x * blockDim.x + threadIdx.x;
  int stride = gridDim.x * blockDim.x;
  const float4* x4 = (const float4*)x;
  uint2* o2 = (uint2*)o;
  for (int j = tid; j < (NEL >> 2); j += stride) {
    int e = j << 2;
    float s = mk_scale(slots[(e >> 11) & 15]);
    float4 v = x4[j];
    u16 a = f2b_exact(quant_val(v.x, s));
    u16 b = f2b_exact(quant_val(v.y, s));
    u16 c = f2b_exact(quant_val(v.z, s));
    u16 d = f2b_exact(quant_val(v.w, s));
    uint2 w; w.x = (u32)a | ((u32)b << 16); w.y = (u32)c | ((u32)d << 16);
    o2[j] = w;
  }
}

// quantize v (global scale) and transpose [B,H,S,D] -> [B,H,D,S]
__global__ void k_quant_vT(const float* __restrict__ x, u16* __restrict__ o, const float* __restrict__ slot) {
  __shared__ u16 lds[64][136];
  float s = mk_scale(*slot);
  int bh = blockIdx.x >> 2;
  int sc0 = (blockIdx.x & 3) << 7;  // 128-row s chunk
  const float4* src = (const float4*)(x + ((size_t)bh * SS + sc0) * DD);
  for (int j = threadIdx.x; j < 2048; j += 256) {
    float4 v = src[j];
    int e = j << 2;
    int srow = e >> 6, d = e & 63;
    lds[d][srow] = f2b_exact(quant_val(v.x, s));
    lds[d + 1][srow] = f2b_exact(quant_val(v.y, s));
    lds[d + 2][srow] = f2b_exact(quant_val(v.z, s));
    lds[d + 3][srow] = f2b_exact(quant_val(v.w, s));
  }
  __syncthreads();
  int d = threadIdx.x >> 2, s0 = (threadIdx.x & 3) << 5;
  u16* dst = o + ((size_t)bh * DD + d) * SS + sc0 + s0;
#pragma unroll
  for (int i = 0; i < 32; i += 8)
    *(uint4*)(dst + i) = *(const uint4*)&lds[d][s0 + i];
}

// C[M,N] = A[M,K] * B[N,K]^T  (both integer-valued bf16; exact in fp32 MFMA accum)
// epilogue: val = acc * (sa*sb[n]) + bias[n]; mode1 -> fp32 [B,NH,S,D]; mode0 -> fp32 [M,N]
__global__ __launch_bounds__(256) void k_gemm(const u16* __restrict__ A, const u16* __restrict__ Bw,
    const float* __restrict__ axslot, const float* __restrict__ sb, const float* __restrict__ bias,
    float* outf, float* outc, int mode) {
  __shared__ u16 As[128][72];
  __shared__ u16 Bs[128][72];
  int tid = threadIdx.x;
  int bm = blockIdx.x << 7, bn = blockIdx.y << 7;
  int wv = tid >> 6, lane = tid & 63, quad = lane >> 4, l16 = lane & 15;
  int wr = (wv >> 1) << 6, wc = (wv & 1) << 6;
  int sr = tid >> 1, sseg = (tid & 1) << 5;
  const u16* Ag = A + (size_t)(bm + sr) * 1024 + sseg;
  const u16* Bg = Bw + (size_t)(bn + sr) * 1024 + sseg;
  f32x4 zero = {0.f, 0.f, 0.f, 0.f};
  f32x4 acc[4][4];
#pragma unroll
  for (int i = 0; i < 4; i++)
#pragma unroll
    for (int j = 0; j < 4; j++) acc[i][j] = zero;
  for (int k0 = 0; k0 < 1024; k0 += 64) {
    uint4 av0 = *(const uint4*)(Ag + k0);
    uint4 av1 = *(const uint4*)(Ag + k0 + 8);
    uint4 av2 = *(const uint4*)(Ag + k0 + 16);
    uint4 av3 = *(const uint4*)(Ag + k0 + 24);
    uint4 bv0 = *(const uint4*)(Bg + k0);
    uint4 bv1 = *(const uint4*)(Bg + k0 + 8);
    uint4 bv2 = *(const uint4*)(Bg + k0 + 16);
    uint4 bv3 = *(const uint4*)(Bg + k0 + 24);
    __syncthreads();
    *(uint4*)&As[sr][sseg] = av0;      *(uint4*)&As[sr][sseg + 8] = av1;
    *(uint4*)&As[sr][sseg + 16] = av2; *(uint4*)&As[sr][sseg + 24] = av3;
    *(uint4*)&Bs[sr][sseg] = bv0;      *(uint4*)&Bs[sr][sseg + 8] = bv1;
    *(uint4*)&Bs[sr][sseg + 16] = bv2; *(uint4*)&Bs[sr][sseg + 24] = bv3;
    __syncthreads();
#pragma unroll
    for (int ks = 0; ks < 2; ks++) {
      bfx8 af[4], bfr[4];
#pragma unroll
      for (int i = 0; i < 4; i++) {
        af[i] = *(const bfx8*)&As[wr + i * 16 + l16][ks * 32 + quad * 8];
        bfr[i] = *(const bfx8*)&Bs[wc + i * 16 + l16][ks * 32 + quad * 8];
      }
#pragma unroll
      for (int i = 0; i < 4; i++)
#pragma unroll
        for (int j = 0; j < 4; j++)
          acc[i][j] = __builtin_amdgcn_mfma_f32_16x16x32_bf16(af[i], bfr[j], acc[i][j], 0, 0, 0);
    }
  }
  float sa = mk_scale(*axslot);
#pragma unroll
  for (int j = 0; j < 4; j++) {
    int col = bn + wc + j * 16 + l16;
    float sc = __fmul_rn(sa, sb[col]);
    float bi = bias[col];
#pragma unroll
    for (int i = 0; i < 4; i++) {
      int row0 = bm + wr + i * 16 + quad * 4;
#pragma unroll
      for (int r = 0; r < 4; r++) {
        float v = __fadd_rn(__fmul_rn(acc[i][j][r], sc), bi);
        int row = row0 + r;
        if (mode) {
          int b = row >> 9, s2 = row & 511, h = col >> 6, d = col & 63;
          outf[((((size_t)b * NHD) + h) * SS + s2) * DD + d] = v;
        } else {
          outc[(size_t)row * HD + col] = v;
        }
      }
    }
  }
}

// pass 1: rowmax + PLA row sums in ONE pass (scores held in registers), K staged in LDS halves.
// grid 2048 = (bh, q-tile of 64), 4 waves each own 16 q-rows x all 512 k.
__global__ __launch_bounds__(256, 2) void k_attn1(const u16* __restrict__ qq, const u16* __restrict__ kq,
    const float* __restrict__ scal, float* __restrict__ minslot,
    float* __restrict__ rowmax, float* __restrict__ rowsum, PLA pla) {
  __shared__ u16 Ks[256][72];        // 36 KB: half of K (256 rows x 64), padded stride
  __shared__ float tbl[12][4];       // {a[i], a[i+1]|1e30, m[i], c[i]}
  __shared__ float redmin[4];
  int tid = threadIdx.x;
  if (tid < 12) {
    tbl[tid][0] = pla.a[tid];
    tbl[tid][1] = (tid < 11) ? pla.a[tid + 1] : 1e30f;
    tbl[tid][2] = pla.m[tid];
    tbl[tid][3] = pla.c[tid];
  }
  int bh = blockIdx.x >> 3;
  int q0 = (blockIdx.x & 7) << 6;
  int wv = tid >> 6, lane = tid & 63, quad = lane >> 4, l16 = lane & 15;
  int rowb = q0 + wv * 16;
  const u16* qbase = qq + ((size_t)bh * SS + rowb) * DD;
  const u16* kg = kq + (size_t)bh * SS * DD;
  bfx8 a0 = *(const bfx8*)(qbase + l16 * DD + quad * 8);
  bfx8 a1 = *(const bfx8*)(qbase + l16 * DD + 32 + quad * 8);
  float sqv = mk_scale(scal[SL_AX_QT + (rowb >> 5)]);
  f32x4 sreg[32];
  float rm[4] = {-INFINITY, -INFINITY, -INFINITY, -INFINITY};
#pragma unroll
  for (int half = 0; half < 2; half++) {
    __syncthreads();
    for (int j = tid; j < 2048; j += 256) {
      int row = j >> 3, seg = (j & 7) * 8;
      *(uint4*)&Ks[row][seg] = *(const uint4*)(kg + (half * 256 + row) * 64 + seg);
    }
    __syncthreads();
#pragma unroll
    for (int t = 0; t < 8; t++) {
      float sk = mk_scale(scal[SL_AX_KT + half * 8 + t]);
      float sc = __fmul_rn(__fmul_rn(0.125f, sqv), sk);
#pragma unroll
      for (int h = 0; h < 2; h++) {
        int cbl = t * 2 + h;
        bfx8 b0 = *(const bfx8*)&Ks[cbl * 16 + l16][quad * 8];
        bfx8 b1 = *(const bfx8*)&Ks[cbl * 16 + l16][32 + quad * 8];
        f32x4 acc = {0.f, 0.f, 0.f, 0.f};
        acc = __builtin_amdgcn_mfma_f32_16x16x32_bf16(a0, b0, acc, 0, 0, 0);
        acc = __builtin_amdgcn_mfma_f32_16x16x32_bf16(a1, b1, acc, 0, 0, 0);
        int cb = half * 16 + cbl;
#pragma unroll
        for (int r = 0; r < 4; r++) {
          float sv_ = __fmul_rn(acc[r], sc);
          sreg[cb][r] = sv_;
          rm[r] = fmaxf(rm[r], sv_);
        }
      }
    }
  }
#pragma unroll
  for (int m = 1; m < 16; m <<= 1)
#pragma unroll
    for (int r = 0; r < 4; r++) rm[r] = fmaxf(rm[r], __shfl_xor(rm[r], m));
  float sums[4] = {0.f, 0.f, 0.f, 0.f};
#pragma unroll
  for (int cb = 0; cb < 32; cb++)
#pragma unroll
    for (int r = 0; r < 4; r++) {
      float xc = fixclip(__fsub_rn(sreg[cb][r], rm[r]));
      sums[r] = __fadd_rn(sums[r], pla_fast(xc, tbl));
    }
#pragma unroll
  for (int m = 1; m < 16; m <<= 1)
#pragma unroll
    for (int r = 0; r < 4; r++) sums[r] += __shfl_xor(sums[r], m);
  if (l16 == 0) {
#pragma unroll
    for (int r = 0; r < 4; r++) {
      int row = bh * SS + rowb + quad * 4 + r;
      rowmax[row] = rm[r];
      rowsum[row] = sums[r];
    }
  }
  // one atomicMin per block
  float mn = fminf(fminf(sums[0], sums[1]), fminf(sums[2], sums[3]));
#pragma unroll
  for (int m = 16; m < 64; m <<= 1) mn = fminf(mn, __shfl_xor(mn, m));
  if (lane == 0) redmin[wv] = mn;
  __syncthreads();
  if (tid == 0) {
    mn = fminf(fminf(redmin[0], redmin[1]), fminf(redmin[2], redmin[3]));
    atomicMin((u32*)minslot, __float_as_uint(mn));
  }
}

// pass 2: recompute scores, quantize probs (global scale from minsum), PV, write ctx fp32 [B,S,H*D]
__global__ __launch_bounds__(256) void k_attn2(const u16* __restrict__ qq, const u16* __restrict__ kq,
    const u16* __restrict__ vqt, const float* __restrict__ scal, const float* __restrict__ rowmax,
    const float* __restrict__ rowsum, float* __restrict__ ctx, PLA pla) {
  __shared__ u16 P[32][520];
  __shared__ float tbl[12][4];
  int tid = threadIdx.x;
  if (tid < 12) {
    tbl[tid][0] = pla.a[tid];
    tbl[tid][1] = (tid < 11) ? pla.a[tid + 1] : 1e30f;
    tbl[tid][2] = pla.m[tid];
    tbl[tid][3] = pla.c[tid];
  }
  __syncthreads();
  int blk = blockIdx.x;
  int bh = blk >> 4;
  int q0 = (blk & 15) << 5;
  int wv = tid >> 6, lane = tid & 63, quad = lane >> 4, l16 = lane & 15;
  int rb = (wv >> 1) * 16;
  int cb0 = (wv & 1) * 16;
  const u16* qbase = qq + ((size_t)bh * SS + q0 + rb) * DD;
  const u16* kbase = kq + (size_t)bh * SS * DD;
  bfx8 a0 = *(const bfx8*)(qbase + l16 * DD + quad * 8);
  bfx8 a1 = *(const bfx8*)(qbase + l16 * DD + 32 + quad * 8);
  float sqv = mk_scale(scal[SL_AX_QT + (q0 >> 5)]);
  float rmx[4], rsm[4];
#pragma unroll
  for (int r = 0; r < 4; r++) {
    int row = bh * SS + q0 + rb + quad * 4 + r;
    rmx[r] = rowmax[row];
    rsm[r] = rowsum[row] + 1e-9f;
  }
  float minsum = scal[SL_MINSUM];
  float mxsm = pla.c[11] / (minsum + 1e-9f);   // == global max(sm): PLA monotone, every row attains x=0
  float scp = mk_scale(mxsm);
#pragma unroll
  for (int t = 0; t < 8; t++) {
    float sk = mk_scale(scal[SL_AX_KT + (cb0 >> 1) + t]);
    float sc = __fmul_rn(__fmul_rn(0.125f, sqv), sk);
#pragma unroll
    for (int h = 0; h < 2; h++) {
      int cb = cb0 + t * 2 + h;
      const u16* kp = kbase + (size_t)(cb * 16 + l16) * DD + quad * 8;
      bfx8 b0 = *(const bfx8*)kp;
      bfx8 b1 = *(const bfx8*)(kp + 32);
      f32x4 acc = {0.f, 0.f, 0.f, 0.f};
      acc = __builtin_amdgcn_mfma_f32_16x16x32_bf16(a0, b0, acc, 0, 0, 0);
      acc = __builtin_amdgcn_mfma_f32_16x16x32_bf16(a1, b1, acc, 0, 0, 0);
#pragma unroll
      for (int r = 0; r < 4; r++) {
        float sh = __fsub_rn(__fmul_rn(acc[r], sc), rmx[r]);
        float e = pla_fast(fixclip(sh), tbl);
        float smv = e / rsm[r];
        float np = fminf(fmaxf(rintf(smv / scp), -127.0f), 127.0f);
        P[rb + quad * 4 + r][cb * 16 + l16] = f2b_exact(np);
      }
    }
  }
  __syncthreads();
  f32x4 acc2[2];
  f32x4 zero = {0.f, 0.f, 0.f, 0.f};
  acc2[0] = zero; acc2[1] = zero;
  const u16* vb = vqt + (size_t)bh * DD * SS;
  int dbase = (wv & 1) * 32;
  int rb2 = (wv >> 1) * 16;
  for (int ks = 0; ks < 16; ks++) {
    bfx8 pa = *(const bfx8*)&P[rb2 + l16][ks * 32 + quad * 8];
#pragma unroll
    for (int j = 0; j < 2; j++) {
      int d = dbase + j * 16 + l16;
      bfx8 vf = *(const bfx8*)(vb + (size_t)d * SS + ks * 32 + quad * 8);
      acc2[j] = __builtin_amdgcn_mfma_f32_16x16x32_bf16(pa, vf, acc2[j], 0, 0, 0);
    }
  }
  float sv = mk_scale(scal[SL_AX_V]);
  float fsc = __fmul_rn(scp, sv);
  int b = bh >> 4, h = bh & 15;
#pragma unroll
  for (int j = 0; j < 2; j++) {
    int d = dbase + j * 16 + l16;
#pragma unroll
    for (int r = 0; r < 4; r++) {
      int srow = q0 + rb2 + quad * 4 + r;
      ctx[((size_t)(b * SS + srow)) * HD + h * DD + d] = __fmul_rn(acc2[j][r], fsc);
    }
  }
}

// host: rebuild _build_pla exactly (float64 linspace mirror + degree-1 OLS, cast to f32)
static void build_pla(PLA* p) {
  double xs[1001], ys[1001];
  for (int i = 0; i < 1001; i++) { double t = (double)i * 0.01; xs[i] = t - 10.0; }
  xs[1000] = 0.0;
  for (int i = 0; i < 1001; i++) ys[i] = exp(xs[i]);
  double es = 10.0 / 12.0;
  double edges[13];
  for (int i = 0; i < 13; i++) { double t = (double)i * es; edges[i] = t - 10.0; }
  edges[12] = 0.0;
  for (int k = 0; k < 12; k++) {
    double sx = 0, sy = 0, sxx = 0, sxy = 0; int n = 0;
    for (int j = 0; j < 1001; j++) {
      if (xs[j] >= edges[k] && xs[j] <= edges[k + 1]) {
        n++; sx += xs[j]; sy += ys[j]; sxx += xs[j] * xs[j]; sxy += xs[j] * ys[j];
      }
    }
    double mx = sx / n, my = sy / n;
    double mm = (sxy - sx * my) / (sxx - sx * mx);
    double cc = my - mm * mx;
    p->m[k] = (float)mm; p->c[k] = (float)cc; p->a[k] = (float)edges[k];
  }
}

extern "C" void kernel_launch(void* const* d_in, const int* in_sizes, int n_in,
                              void* d_out, int out_size, void* d_ws, size_t ws_size,
                              hipStream_t stream) {
  const float* hs = (const float*)d_in[0];
  const float* Wq = (const float*)d_in[1]; const float* bq = (const float*)d_in[2];
  const float* Wk = (const float*)d_in[3]; const float* bk = (const float*)d_in[4];
  const float* Wv = (const float*)d_in[5]; const float* bv = (const float*)d_in[6];
  const float* Wo = (const float*)d_in[7]; const float* bo = (const float*)d_in[8];
  float* out = (float*)d_out;
  char* ws = (char*)d_ws;
  float* scal = (float*)ws;                         // 64 scalar slots
  float* sw = (float*)(ws + 4096);                  // 4*1024 per-row weight scales
  float* rowmax = (float*)(ws + (64 << 10));        // 131072 f32
  float* rowsum = (float*)(ws + (576 << 10));       // 131072 f32
  u16* wb = (u16*)(ws + (2ll << 20));               // 4 x [1024,1024] bf16-int
  u16* xq = (u16*)(ws + (10ll << 20));              // [8192,1024] bf16-int (later reused as ctxq)
  u16* qq = (u16*)(ws + (26ll << 20));              // [B,H,S,D]
  u16* kq = (u16*)(ws + (42ll << 20));              // [B,H,S,D]
  u16* vqt = (u16*)(ws + (58ll << 20));             // [B,H,D,S]
  float* tmp = (float*)(ws + (74ll << 20));         // [8192,1024] fp32 temp (q/k/v then ctx)
  u16* ctxq = xq;

  PLA pla;
  build_pla(&pla);

  k_init<<<1, 64, 0, stream>>>(scal);
  k_wprep<<<1024, 256, 0, stream>>>(Wq, sw + 0, wb + 0);
  k_wprep<<<1024, 256, 0, stream>>>(Wk, sw + 1024, wb + 1048576);
  k_wprep<<<1024, 256, 0, stream>>>(Wv, sw + 2048, wb + 2097152);
  k_wprep<<<1024, 256, 0, stream>>>(Wo, sw + 3072, wb + 3145728);
  k_absmax_f32<<<512, 256, 0, stream>>>(hs, NEL, scal + SL_AX_X);
  k_quant_f32<<<1024, 256, 0, stream>>>(hs, xq, scal + SL_AX_X);

  const float* biases[3] = {bq, bk, bv};
  for (int z = 0; z < 3; z++) {
    k_gemm<<<dim3(64, 8), 256, 0, stream>>>(xq, wb + (size_t)z * 1048576, scal + SL_AX_X,
                                            sw + z * 1024, biases[z], tmp, (float*)0, 1);
    if (z == 0) {
      k_absmax_tiles<<<4096, 256, 0, stream>>>(tmp, scal + SL_AX_QT);
      k_quant_tiles<<<1024, 256, 0, stream>>>(tmp, qq, scal + SL_AX_QT);
    } else if (z == 1) {
      k_absmax_tiles<<<4096, 256, 0, stream>>>(tmp, scal + SL_AX_KT);
      k_quant_tiles<<<1024, 256, 0, stream>>>(tmp, kq, scal + SL_AX_KT);
    } else {
      k_absmax_f32<<<512, 256, 0, stream>>>(tmp, NEL, scal + SL_AX_V);
      k_quant_vT<<<1024, 256, 0, stream>>>(tmp, vqt, scal + SL_AX_V);
    }
  }

  k_attn1<<<2048, 256, 0, stream>>>(qq, kq, scal, scal + SL_MINSUM, rowmax, rowsum, pla);
  k_attn2<<<4096, 256, 0, stream>>>(qq, kq, vqt, scal, rowmax, rowsum, tmp, pla);

  k_absmax_f32<<<512, 256, 0, stream>>>(tmp, NEL, scal + SL_AX_CTX);
  k_quant_f32<<<1024, 256, 0, stream>>>(tmp, ctxq, scal + SL_AX_CTX);
  k_gemm<<<dim3(64, 8), 256, 0, stream>>>(ctxq, wb + 3145728, scal + SL_AX_CTX,
                                          sw + 3072, bo, (float*)0, out, 0);
}